// Round 2
// baseline (1425.511 us; speedup 1.0000x reference)
//
#include <hip/hip_runtime.h>
#include <math.h>

#define BATCH 65536

// ws layout (floats): [0,514) diff accumulators; [514,516) r0; [516,528) r1;
// [528,600) r2; [600,1032) r3; [1032,1572) Wfe[3][180]
#define WS_DIFF 0
#define WS_R0   514
#define WS_R1   516
#define WS_R2   528
#define WS_R3   600
#define WS_WFE  1032

__device__ __forceinline__ float fast_tanh(float x) {
    // tanh(x) = 1 - 2/(exp(2x)+1); graceful at +-inf (exp->inf -> 1, exp->0 -> -1)
    float e = __expf(2.0f * x);
    return 1.0f - 2.0f * __builtin_amdgcn_rcpf(e + 1.0f);
}

// One expander layer: n = M*REPS blocks; block j input = rprev[j%M] * S.
// Accumulates S_next = sum_j out_j, and batch-mean diff partials into diff[].
template<int M, int REPS, bool HASR>
__device__ __forceinline__ void run_layer(
    const float* __restrict__ W1, const float* __restrict__ b1,
    const float* __restrict__ W2, const float* __restrict__ b2,
    const float* __restrict__ rprev,
    float& s0, float& s1, float& s2,
    float* __restrict__ diff, int diff_base, int lane)
{
    float a0 = 0.f, a1 = 0.f, a2 = 0.f;
    float p0 = 0.f, p1 = 0.f, p2 = 0.f;
    for (int rep = 0; rep < REPS; ++rep) {
        for (int i = 0; i < M; ++i) {
            const int j = rep * M + i;
            const float c = HASR ? rprev[i] : 1.0f;
            const float t0 = c * s0, t1 = c * s1, t2 = c * s2;
            const float* __restrict__ w1 = W1 + j * 9;
            const float* __restrict__ w2 = W2 + j * 9;
            const float* __restrict__ B1 = b1 + j * 3;
            const float* __restrict__ B2 = b2 + j * 3;
            float h0 = fast_tanh(B1[0] + t0 * w1[0] + t1 * w1[3] + t2 * w1[6]);
            float h1 = fast_tanh(B1[1] + t0 * w1[1] + t1 * w1[4] + t2 * w1[7]);
            float h2 = fast_tanh(B1[2] + t0 * w1[2] + t1 * w1[5] + t2 * w1[8]);
            float o0 = B2[0] + h0 * w2[0] + h1 * w2[3] + h2 * w2[6];
            float o1 = B2[1] + h0 * w2[1] + h1 * w2[4] + h2 * w2[7];
            float o2 = B2[2] + h0 * w2[2] + h1 * w2[5] + h2 * w2[8];
            a0 += o0; a1 += o1; a2 += o2;
            if (j > 0) {
                float d = fabsf(o0 - p0) + fabsf(o1 - p1) + fabsf(o2 - p2);
                #pragma unroll
                for (int off = 32; off; off >>= 1) d += __shfl_xor(d, off);
                if (lane == 0) atomicAdd(&diff[diff_base + j - 1], d);
            }
            p0 = o0; p1 = o1; p2 = o2;
        }
    }
    s0 = a0; s1 = a1; s2 = a2;
}

// Zero diff accumulators and compute row sums r_l[i] = sum_j R_l[i][j].
__global__ void precompute_r(const float* __restrict__ R0, const float* __restrict__ R1,
                             const float* __restrict__ R2, const float* __restrict__ R3,
                             float* __restrict__ ws)
{
    const int k = blockIdx.x * blockDim.x + threadIdx.x;
    if (k < 514) ws[WS_DIFF + k] = 0.0f;
    if (k < 2) {
        float s = 0.f;
        for (int j = 0; j < 2; ++j) s += R0[k * 2 + j];
        ws[WS_R0 + k] = s;
    } else if (k < 14) {
        const int i = k - 2; float s = 0.f;
        for (int j = 0; j < 12; ++j) s += R1[i * 12 + j];
        ws[WS_R1 + i] = s;
    } else if (k < 86) {
        const int i = k - 14; float s = 0.f;
        for (int j = 0; j < 72; ++j) s += R2[i * 72 + j];
        ws[WS_R2 + i] = s;
    } else if (k < 518) {
        const int i = k - 86; float s = 0.f;
        for (int j = 0; j < 432; ++j) s += R3[i * 432 + j];
        ws[WS_R3 + i] = s;
    }
}

// Wfe[f*180+o] = sum_i r3[i] * W_final[(3i+f)*180 + o]
__global__ void precompute_wfe(const float* __restrict__ Wf,
                               const float* __restrict__ r3,
                               float* __restrict__ wfe)
{
    const int k = blockIdx.x * blockDim.x + threadIdx.x;
    if (k >= 540) return;
    const int f = k / 180, o = k - f * 180;
    float s = 0.f;
    for (int i = 0; i < 432; ++i) s += r3[i] * Wf[(3 * i + f) * 180 + o];
    wfe[k] = s;
}

__global__ __launch_bounds__(256) void fractal_main(
    const float* __restrict__ x,
    const float* __restrict__ Wl, const float* __restrict__ Wi,
    const float* __restrict__ W1_0, const float* __restrict__ b1_0,
    const float* __restrict__ W2_0, const float* __restrict__ b2_0,
    const float* __restrict__ W1_1, const float* __restrict__ b1_1,
    const float* __restrict__ W2_1, const float* __restrict__ b2_1,
    const float* __restrict__ W1_2, const float* __restrict__ b1_2,
    const float* __restrict__ W2_2, const float* __restrict__ b2_2,
    const float* __restrict__ W1_3, const float* __restrict__ b1_3,
    const float* __restrict__ W2_3, const float* __restrict__ b2_3,
    const float* __restrict__ b_final,
    float* __restrict__ diff,
    const float* __restrict__ r0, const float* __restrict__ r1,
    const float* __restrict__ r2, const float* __restrict__ wfe,
    float* __restrict__ out)
{
    const int b = blockIdx.x * blockDim.x + threadIdx.x;
    const int lane = threadIdx.x & 63;

    // ---- QuantumTrinity seed: v = (L + sin(2piL/3) + E@Wi)/3 ----
    const float* __restrict__ xr = x + (size_t)b * 90;
    float L0 = 0.f, L1 = 0.f, L2 = 0.f;
    for (int k = 0; k < 45; ++k) {
        const float2 xv = *reinterpret_cast<const float2*>(xr + 2 * k);
        const float* __restrict__ w = Wl + 6 * k;
        L0 += xv.x * w[0] + xv.y * w[3];
        L1 += xv.x * w[1] + xv.y * w[4];
        L2 += xv.x * w[2] + xv.y * w[5];
    }
    const float CC = 2.0943951023931953f; // 2*pi/3
    const float E0 = sinf(CC * L0), E1 = sinf(CC * L1), E2 = sinf(CC * L2);
    const float I0 = E0 * Wi[0] + E1 * Wi[3] + E2 * Wi[6];
    const float I1 = E0 * Wi[1] + E1 * Wi[4] + E2 * Wi[7];
    const float I2 = E0 * Wi[2] + E1 * Wi[5] + E2 * Wi[8];
    float s0 = (L0 + E0 + I0) * (1.0f / 3.0f);
    float s1 = (L1 + E1 + I1) * (1.0f / 3.0f);
    float s2 = (L2 + E2 + I2) * (1.0f / 3.0f);

    // ---- 4 expanders; state is just the 3-vector S ----
    run_layer<1, 2, false>(W1_0, b1_0, W2_0, b2_0, nullptr, s0, s1, s2, diff, 0,  lane);
    run_layer<2, 6, true >(W1_1, b1_1, W2_1, b2_1, r0,      s0, s1, s2, diff, 1,  lane);
    run_layer<12, 6, true>(W1_2, b1_2, W2_2, b2_2, r1,      s0, s1, s2, diff, 12, lane);
    run_layer<72, 6, true>(W1_3, b1_3, W2_3, b2_3, r2,      s0, s1, s2, diff, 83, lane);

    // ---- final: out[b] = S3 @ Wfe + b_final  (3x180) ----
    float* __restrict__ orow = out + (size_t)b * 180;
    for (int o = 0; o < 180; o += 4) {
        float4 r;
        r.x = b_final[o + 0] + s0 * wfe[o + 0] + s1 * wfe[180 + o + 0] + s2 * wfe[360 + o + 0];
        r.y = b_final[o + 1] + s0 * wfe[o + 1] + s1 * wfe[180 + o + 1] + s2 * wfe[360 + o + 1];
        r.z = b_final[o + 2] + s0 * wfe[o + 2] + s1 * wfe[180 + o + 2] + s2 * wfe[360 + o + 2];
        r.w = b_final[o + 3] + s0 * wfe[o + 3] + s1 * wfe[180 + o + 3] + s2 * wfe[360 + o + 3];
        *reinterpret_cast<float4*>(orow + o) = r;
    }
}

// stab[k]: first entry of each layer = 1.0, else max(0, 1 - diff/(B*3))
__global__ void finalize_stab(const float* __restrict__ diff, float* __restrict__ stab)
{
    const int k = blockIdx.x * blockDim.x + threadIdx.x;
    if (k >= 518) return;
    int pos, dbase;
    if (k < 2)       { pos = k;      dbase = 0;  }
    else if (k < 14) { pos = k - 2;  dbase = 1;  }
    else if (k < 86) { pos = k - 14; dbase = 12; }
    else             { pos = k - 86; dbase = 83; }
    float v;
    if (pos == 0) v = 1.0f;
    else v = fmaxf(0.0f, 1.0f - diff[dbase + pos - 1] * (1.0f / 196608.0f));
    stab[k] = v;
}

extern "C" void kernel_launch(void* const* d_in, const int* in_sizes, int n_in,
                              void* d_out, int out_size, void* d_ws, size_t ws_size,
                              hipStream_t stream)
{
    const float* x    = (const float*)d_in[0];
    const float* Wl   = (const float*)d_in[1];
    const float* Wi   = (const float*)d_in[2];
    const float* W1_0 = (const float*)d_in[3];
    const float* b1_0 = (const float*)d_in[4];
    const float* W2_0 = (const float*)d_in[5];
    const float* b2_0 = (const float*)d_in[6];
    const float* R0   = (const float*)d_in[7];
    const float* W1_1 = (const float*)d_in[8];
    const float* b1_1 = (const float*)d_in[9];
    const float* W2_1 = (const float*)d_in[10];
    const float* b2_1 = (const float*)d_in[11];
    const float* R1   = (const float*)d_in[12];
    const float* W1_2 = (const float*)d_in[13];
    const float* b1_2 = (const float*)d_in[14];
    const float* W2_2 = (const float*)d_in[15];
    const float* b2_2 = (const float*)d_in[16];
    const float* R2   = (const float*)d_in[17];
    const float* W1_3 = (const float*)d_in[18];
    const float* b1_3 = (const float*)d_in[19];
    const float* W2_3 = (const float*)d_in[20];
    const float* b2_3 = (const float*)d_in[21];
    const float* R3   = (const float*)d_in[22];
    const float* Wf   = (const float*)d_in[23];
    const float* bf   = (const float*)d_in[24];

    float* out = (float*)d_out;
    float* ws  = (float*)d_ws;

    precompute_r<<<dim3(3), dim3(256), 0, stream>>>(R0, R1, R2, R3, ws);
    precompute_wfe<<<dim3(3), dim3(256), 0, stream>>>(Wf, ws + WS_R3, ws + WS_WFE);
    fractal_main<<<dim3(BATCH / 256), dim3(256), 0, stream>>>(
        x, Wl, Wi,
        W1_0, b1_0, W2_0, b2_0,
        W1_1, b1_1, W2_1, b2_1,
        W1_2, b1_2, W2_2, b2_2,
        W1_3, b1_3, W2_3, b2_3,
        bf,
        ws + WS_DIFF, ws + WS_R0, ws + WS_R1, ws + WS_R2, ws + WS_WFE,
        out);
    finalize_stab<<<dim3(3), dim3(256), 0, stream>>>(ws + WS_DIFF, out + (size_t)BATCH * 180);
}

// Round 3
// 535.863 us; speedup vs baseline: 2.6602x; 2.6602x over previous
//
#include <hip/hip_runtime.h>
#include <math.h>

#define BATCH  65536
#define NWAVES 1024         // BATCH / 64
#define NDIFF  514          // (2-1)+(12-1)+(72-1)+(432-1)

// ws layout (floats): [0, 514*1024) per-wave diff partials; then r0,r1,r2,r3, Wfe
#define WS_PART 0
#define WS_R0   (NDIFF * NWAVES)       // 526336
#define WS_R1   (WS_R0 + 2)
#define WS_R2   (WS_R1 + 12)
#define WS_R3   (WS_R2 + 72)
#define WS_WFE  (WS_R3 + 432)          // 540 floats; total 527394 floats ~= 2.06 MB

__device__ __forceinline__ float fast_tanh(float x) {
    // tanh(x) = 1 - 2/(exp(2x)+1); graceful at +-inf
    float e = __expf(2.0f * x);
    return 1.0f - 2.0f * __builtin_amdgcn_rcpf(e + 1.0f);
}

// One expander layer: n = M*REPS blocks; block j input = rprev[j%M] * S.
// Accumulates S_next = sum_j out_j; per-wave diff partial -> plain store (no atomics).
template<int M, int REPS, bool HASR>
__device__ __forceinline__ void run_layer(
    const float* __restrict__ W1, const float* __restrict__ b1,
    const float* __restrict__ W2, const float* __restrict__ b2,
    const float* __restrict__ rprev,
    float& s0, float& s1, float& s2,
    float* __restrict__ diffp, int diff_base, int lane, int gwave)
{
    float a0 = 0.f, a1 = 0.f, a2 = 0.f;
    float p0 = 0.f, p1 = 0.f, p2 = 0.f;
    for (int rep = 0; rep < REPS; ++rep) {
        #pragma unroll 4
        for (int i = 0; i < M; ++i) {
            const int j = rep * M + i;
            const float c = HASR ? rprev[i] : 1.0f;
            const float t0 = c * s0, t1 = c * s1, t2 = c * s2;
            const float* __restrict__ w1 = W1 + j * 9;
            const float* __restrict__ w2 = W2 + j * 9;
            const float* __restrict__ B1 = b1 + j * 3;
            const float* __restrict__ B2 = b2 + j * 3;
            float h0 = fast_tanh(B1[0] + t0 * w1[0] + t1 * w1[3] + t2 * w1[6]);
            float h1 = fast_tanh(B1[1] + t0 * w1[1] + t1 * w1[4] + t2 * w1[7]);
            float h2 = fast_tanh(B1[2] + t0 * w1[2] + t1 * w1[5] + t2 * w1[8]);
            float o0 = B2[0] + h0 * w2[0] + h1 * w2[3] + h2 * w2[6];
            float o1 = B2[1] + h0 * w2[1] + h1 * w2[4] + h2 * w2[7];
            float o2 = B2[2] + h0 * w2[2] + h1 * w2[5] + h2 * w2[8];
            a0 += o0; a1 += o1; a2 += o2;
            if (j > 0) {
                float d = fabsf(o0 - p0) + fabsf(o1 - p1) + fabsf(o2 - p2);
                #pragma unroll
                for (int off = 32; off; off >>= 1) d += __shfl_xor(d, off);
                if (lane == 0)
                    diffp[(size_t)(diff_base + j - 1) * NWAVES + gwave] = d;
            }
            p0 = o0; p1 = o1; p2 = o2;
        }
    }
    s0 = a0; s1 = a1; s2 = a2;
}

// Row sums r_l[i] = sum_j R_l[i][j].
__global__ void precompute_r(const float* __restrict__ R0, const float* __restrict__ R1,
                             const float* __restrict__ R2, const float* __restrict__ R3,
                             float* __restrict__ ws)
{
    const int k = blockIdx.x * blockDim.x + threadIdx.x;
    if (k < 2) {
        float s = 0.f;
        for (int j = 0; j < 2; ++j) s += R0[k * 2 + j];
        ws[WS_R0 + k] = s;
    } else if (k < 14) {
        const int i = k - 2; float s = 0.f;
        for (int j = 0; j < 12; ++j) s += R1[i * 12 + j];
        ws[WS_R1 + i] = s;
    } else if (k < 86) {
        const int i = k - 14; float s = 0.f;
        for (int j = 0; j < 72; ++j) s += R2[i * 72 + j];
        ws[WS_R2 + i] = s;
    } else if (k < 518) {
        const int i = k - 86; float s = 0.f;
        for (int j = 0; j < 432; ++j) s += R3[i * 432 + j];
        ws[WS_R3 + i] = s;
    }
}

// Wfe[f*180+o] = sum_i r3[i] * W_final[(3i+f)*180 + o]
__global__ void precompute_wfe(const float* __restrict__ Wf,
                               const float* __restrict__ r3,
                               float* __restrict__ wfe)
{
    const int k = blockIdx.x * blockDim.x + threadIdx.x;
    if (k >= 540) return;
    const int f = k / 180, o = k - f * 180;
    float s = 0.f;
    for (int i = 0; i < 432; ++i) s += r3[i] * Wf[(3 * i + f) * 180 + o];
    wfe[k] = s;
}

__global__ __launch_bounds__(256) void fractal_main(
    const float* __restrict__ x,
    const float* __restrict__ Wl, const float* __restrict__ Wi,
    const float* __restrict__ W1_0, const float* __restrict__ b1_0,
    const float* __restrict__ W2_0, const float* __restrict__ b2_0,
    const float* __restrict__ W1_1, const float* __restrict__ b1_1,
    const float* __restrict__ W2_1, const float* __restrict__ b2_1,
    const float* __restrict__ W1_2, const float* __restrict__ b1_2,
    const float* __restrict__ W2_2, const float* __restrict__ b2_2,
    const float* __restrict__ W1_3, const float* __restrict__ b1_3,
    const float* __restrict__ W2_3, const float* __restrict__ b2_3,
    const float* __restrict__ b_final,
    float* __restrict__ diffp,
    const float* __restrict__ r0, const float* __restrict__ r1,
    const float* __restrict__ r2, const float* __restrict__ wfe,
    float* __restrict__ out)
{
    const int b = blockIdx.x * blockDim.x + threadIdx.x;
    const int lane = threadIdx.x & 63;
    const int gwave = (blockIdx.x << 2) | (threadIdx.x >> 6);

    // ---- QuantumTrinity seed: v = (L + sin(2piL/3) + E@Wi)/3 ----
    const float* __restrict__ xr = x + (size_t)b * 90;
    float L0 = 0.f, L1 = 0.f, L2 = 0.f;
    for (int k = 0; k < 45; ++k) {
        const float2 xv = *reinterpret_cast<const float2*>(xr + 2 * k);
        const float* __restrict__ w = Wl + 6 * k;
        L0 += xv.x * w[0] + xv.y * w[3];
        L1 += xv.x * w[1] + xv.y * w[4];
        L2 += xv.x * w[2] + xv.y * w[5];
    }
    const float CC = 2.0943951023931953f; // 2*pi/3
    const float E0 = sinf(CC * L0), E1 = sinf(CC * L1), E2 = sinf(CC * L2);
    const float I0 = E0 * Wi[0] + E1 * Wi[3] + E2 * Wi[6];
    const float I1 = E0 * Wi[1] + E1 * Wi[4] + E2 * Wi[7];
    const float I2 = E0 * Wi[2] + E1 * Wi[5] + E2 * Wi[8];
    float s0 = (L0 + E0 + I0) * (1.0f / 3.0f);
    float s1 = (L1 + E1 + I1) * (1.0f / 3.0f);
    float s2 = (L2 + E2 + I2) * (1.0f / 3.0f);

    // ---- 4 expanders; state is just the 3-vector S ----
    run_layer<1, 2, false>(W1_0, b1_0, W2_0, b2_0, nullptr, s0, s1, s2, diffp, 0,  lane, gwave);
    run_layer<2, 6, true >(W1_1, b1_1, W2_1, b2_1, r0,      s0, s1, s2, diffp, 1,  lane, gwave);
    run_layer<12, 6, true>(W1_2, b1_2, W2_2, b2_2, r1,      s0, s1, s2, diffp, 12, lane, gwave);
    run_layer<72, 6, true>(W1_3, b1_3, W2_3, b2_3, r2,      s0, s1, s2, diffp, 83, lane, gwave);

    // ---- final: out[b] = S3 @ Wfe + b_final  (3x180) ----
    float* __restrict__ orow = out + (size_t)b * 180;
    for (int o = 0; o < 180; o += 4) {
        float4 r;
        r.x = b_final[o + 0] + s0 * wfe[o + 0] + s1 * wfe[180 + o + 0] + s2 * wfe[360 + o + 0];
        r.y = b_final[o + 1] + s0 * wfe[o + 1] + s1 * wfe[180 + o + 1] + s2 * wfe[360 + o + 1];
        r.z = b_final[o + 2] + s0 * wfe[o + 2] + s1 * wfe[180 + o + 2] + s2 * wfe[360 + o + 2];
        r.w = b_final[o + 3] + s0 * wfe[o + 3] + s1 * wfe[180 + o + 3] + s2 * wfe[360 + o + 3];
        *reinterpret_cast<float4*>(orow + o) = r;
    }
}

// One block per stab entry: sum the 1024 per-wave partials, write stab.
__global__ __launch_bounds__(256) void reduce_stab(const float* __restrict__ diffp,
                                                   float* __restrict__ stab)
{
    const int k = blockIdx.x;
    int pos, dbase;
    if (k < 2)       { pos = k;      dbase = 0;  }
    else if (k < 14) { pos = k - 2;  dbase = 1;  }
    else if (k < 86) { pos = k - 14; dbase = 12; }
    else             { pos = k - 86; dbase = 83; }
    if (pos == 0) { if (threadIdx.x == 0) stab[k] = 1.0f; return; }

    const int d = dbase + pos - 1;
    const int t = threadIdx.x;
    const float* __restrict__ p = diffp + (size_t)d * NWAVES;
    float s = p[t] + p[t + 256] + p[t + 512] + p[t + 768];
    #pragma unroll
    for (int off = 32; off; off >>= 1) s += __shfl_xor(s, off);
    __shared__ float red[4];
    if ((t & 63) == 0) red[t >> 6] = s;
    __syncthreads();
    if (t == 0) {
        const float tot = red[0] + red[1] + red[2] + red[3];
        stab[k] = fmaxf(0.0f, 1.0f - tot * (1.0f / 196608.0f));
    }
}

extern "C" void kernel_launch(void* const* d_in, const int* in_sizes, int n_in,
                              void* d_out, int out_size, void* d_ws, size_t ws_size,
                              hipStream_t stream)
{
    const float* x    = (const float*)d_in[0];
    const float* Wl   = (const float*)d_in[1];
    const float* Wi   = (const float*)d_in[2];
    const float* W1_0 = (const float*)d_in[3];
    const float* b1_0 = (const float*)d_in[4];
    const float* W2_0 = (const float*)d_in[5];
    const float* b2_0 = (const float*)d_in[6];
    const float* R0   = (const float*)d_in[7];
    const float* W1_1 = (const float*)d_in[8];
    const float* b1_1 = (const float*)d_in[9];
    const float* W2_1 = (const float*)d_in[10];
    const float* b2_1 = (const float*)d_in[11];
    const float* R1   = (const float*)d_in[12];
    const float* W1_2 = (const float*)d_in[13];
    const float* b1_2 = (const float*)d_in[14];
    const float* W2_2 = (const float*)d_in[15];
    const float* b2_2 = (const float*)d_in[16];
    const float* R2   = (const float*)d_in[17];
    const float* W1_3 = (const float*)d_in[18];
    const float* b1_3 = (const float*)d_in[19];
    const float* W2_3 = (const float*)d_in[20];
    const float* b2_3 = (const float*)d_in[21];
    const float* R3   = (const float*)d_in[22];
    const float* Wf   = (const float*)d_in[23];
    const float* bf   = (const float*)d_in[24];

    float* out = (float*)d_out;
    float* ws  = (float*)d_ws;

    precompute_r<<<dim3(3), dim3(256), 0, stream>>>(R0, R1, R2, R3, ws);
    precompute_wfe<<<dim3(3), dim3(256), 0, stream>>>(Wf, ws + WS_R3, ws + WS_WFE);
    fractal_main<<<dim3(BATCH / 256), dim3(256), 0, stream>>>(
        x, Wl, Wi,
        W1_0, b1_0, W2_0, b2_0,
        W1_1, b1_1, W2_1, b2_1,
        W1_2, b1_2, W2_2, b2_2,
        W1_3, b1_3, W2_3, b2_3,
        bf,
        ws + WS_PART, ws + WS_R0, ws + WS_R1, ws + WS_R2, ws + WS_WFE,
        out);
    reduce_stab<<<dim3(518), dim3(256), 0, stream>>>(ws + WS_PART, out + (size_t)BATCH * 180);
}

// Round 5
// 287.933 us; speedup vs baseline: 4.9508x; 1.8611x over previous
//
#include <hip/hip_runtime.h>
#include <math.h>

#define BATCH  65536
#define NWG    1024          // fractal_main workgroups; one WG owns 64 batch elems
#define NDIFF  514           // (2-1)+(12-1)+(72-1)+(432-1)

// ws layout (floats), offsets kept 16B-aligned where float4 loads occur:
#define WS_PART 0
#define WS_R0   (NDIFF * NWG)          // 526336 (per-WG diff partials end here)
#define WS_R1   (WS_R0 + 4)            // pad 2->4
#define WS_R2   (WS_R1 + 12)
#define WS_R3   (WS_R2 + 72)
#define WS_WFE  (WS_R3 + 432)          // 526856 -> byte offset % 16 == 0

__device__ __forceinline__ float fast_tanh(float x) {
    float e = __expf(2.0f * x);
    return 1.0f - 2.0f * __builtin_amdgcn_rcpf(e + 1.0f);
}

// Compute one fractal block j: input = c*S, output o0..o2.
__device__ __forceinline__ void block_fwd(
    const float* __restrict__ W1, const float* __restrict__ b1,
    const float* __restrict__ W2, const float* __restrict__ b2,
    int j, float c, float s0, float s1, float s2,
    float& o0, float& o1, float& o2)
{
    const float t0 = c * s0, t1 = c * s1, t2 = c * s2;
    const float* __restrict__ w1 = W1 + j * 9;
    const float* __restrict__ w2 = W2 + j * 9;
    const float* __restrict__ B1 = b1 + j * 3;
    const float* __restrict__ B2 = b2 + j * 3;
    float h0 = fast_tanh(B1[0] + t0 * w1[0] + t1 * w1[3] + t2 * w1[6]);
    float h1 = fast_tanh(B1[1] + t0 * w1[1] + t1 * w1[4] + t2 * w1[7]);
    float h2 = fast_tanh(B1[2] + t0 * w1[2] + t1 * w1[5] + t2 * w1[8]);
    o0 = B2[0] + h0 * w2[0] + h1 * w2[3] + h2 * w2[6];
    o1 = B2[1] + h0 * w2[1] + h1 * w2[4] + h2 * w2[7];
    o2 = B2[2] + h0 * w2[2] + h1 * w2[5] + h2 * w2[8];
}

// Wave-local slice [lo,hi) of one expander layer. Produces partial sum a,
// writes per-WG diff partials (one full-wave butterfly per j, lane0 store).
template<int M, bool HASR>
__device__ __forceinline__ void run_range(
    const float* __restrict__ W1, const float* __restrict__ b1,
    const float* __restrict__ W2, const float* __restrict__ b2,
    const float* __restrict__ rprev,
    int lo, int hi,
    float s0, float s1, float s2,
    float& a0, float& a1, float& a2,
    float* __restrict__ diffp, int dbase, int wg, int lane)
{
    a0 = 0.f; a1 = 0.f; a2 = 0.f;
    if (lo >= hi) return;                      // wave-uniform
    float p0 = 0.f, p1 = 0.f, p2 = 0.f;
    if (lo > 0) {                              // prologue: prev block for first diff
        const int il = (lo - 1) % M;
        const float c = HASR ? rprev[il] : 1.0f;
        block_fwd(W1, b1, W2, b2, lo - 1, c, s0, s1, s2, p0, p1, p2);
    }
    int i = lo % M;
    for (int j = lo; j < hi; ++j) {
        const float c = HASR ? rprev[i] : 1.0f;
        float o0, o1, o2;
        block_fwd(W1, b1, W2, b2, j, c, s0, s1, s2, o0, o1, o2);
        a0 += o0; a1 += o1; a2 += o2;
        if (j > 0) {
            float d = fabsf(o0 - p0) + fabsf(o1 - p1) + fabsf(o2 - p2);
            #pragma unroll
            for (int off = 32; off; off >>= 1) d += __shfl_xor(d, off);
            if (lane == 0) diffp[(size_t)(dbase + j - 1) * NWG + wg] = d;
        }
        p0 = o0; p1 = o1; p2 = o2;
        if (++i == M) i = 0;
    }
}

__global__ void precompute_r(const float* __restrict__ R0, const float* __restrict__ R1,
                             const float* __restrict__ R2, const float* __restrict__ R3,
                             float* __restrict__ ws)
{
    const int k = blockIdx.x * blockDim.x + threadIdx.x;
    if (k < 2) {
        float s = 0.f;
        for (int j = 0; j < 2; ++j) s += R0[k * 2 + j];
        ws[WS_R0 + k] = s;
    } else if (k < 14) {
        const int i = k - 2; float s = 0.f;
        for (int j = 0; j < 12; ++j) s += R1[i * 12 + j];
        ws[WS_R1 + i] = s;
    } else if (k < 86) {
        const int i = k - 14; float s = 0.f;
        for (int j = 0; j < 72; ++j) s += R2[i * 72 + j];
        ws[WS_R2 + i] = s;
    } else if (k < 518) {
        const int i = k - 86; float s = 0.f;
        for (int j = 0; j < 432; ++j) s += R3[i * 432 + j];
        ws[WS_R3 + i] = s;
    }
}

__global__ void precompute_wfe(const float* __restrict__ Wf,
                               const float* __restrict__ r3,
                               float* __restrict__ wfe)
{
    const int k = blockIdx.x * blockDim.x + threadIdx.x;
    if (k >= 540) return;
    const int f = k / 180, o = k - f * 180;
    float s = 0.f;
    for (int i = 0; i < 432; ++i) s += r3[i] * Wf[(3 * i + f) * 180 + o];
    wfe[k] = s;
}

__global__ __launch_bounds__(512, 8) void fractal_main(
    const float* __restrict__ x,
    const float* __restrict__ Wl, const float* __restrict__ Wi,
    const float* __restrict__ W1_0, const float* __restrict__ b1_0,
    const float* __restrict__ W2_0, const float* __restrict__ b2_0,
    const float* __restrict__ W1_1, const float* __restrict__ b1_1,
    const float* __restrict__ W2_1, const float* __restrict__ b2_1,
    const float* __restrict__ W1_2, const float* __restrict__ b1_2,
    const float* __restrict__ W2_2, const float* __restrict__ b2_2,
    const float* __restrict__ W1_3, const float* __restrict__ b1_3,
    const float* __restrict__ W2_3, const float* __restrict__ b2_3,
    const float* __restrict__ b_final,
    float* __restrict__ diffp,
    const float* __restrict__ r0, const float* __restrict__ r1,
    const float* __restrict__ r2, const float* __restrict__ wfe,
    float* __restrict__ out)
{
    __shared__ float comb[2][8][3][64];   // [buf][wave][component][lane]
    __shared__ float Sout[3][64];

    const int lane = threadIdx.x & 63;
    const int w    = threadIdx.x >> 6;    // wave id 0..7
    const int wg   = blockIdx.x;
    const int b    = wg * 64 + lane;

    // ---- trinity seed, split over waves: wave w does float2 chunks w, w+8, ... ----
    const float* __restrict__ xr = x + (size_t)b * 90;
    float L0 = 0.f, L1 = 0.f, L2 = 0.f;
    for (int k = w; k < 45; k += 8) {
        const float2 xv = *reinterpret_cast<const float2*>(xr + 2 * k);
        const float* __restrict__ wl = Wl + 6 * k;
        L0 += xv.x * wl[0] + xv.y * wl[3];
        L1 += xv.x * wl[1] + xv.y * wl[4];
        L2 += xv.x * wl[2] + xv.y * wl[5];
    }
    comb[0][w][0][lane] = L0; comb[0][w][1][lane] = L1; comb[0][w][2][lane] = L2;
    __syncthreads();
    L0 = L1 = L2 = 0.f;
    #pragma unroll
    for (int q = 0; q < 8; ++q) {
        L0 += comb[0][q][0][lane];
        L1 += comb[0][q][1][lane];
        L2 += comb[0][q][2][lane];
    }
    const float CC = 2.0943951023931953f; // 2*pi/3
    const float E0 = __sinf(CC * L0), E1 = __sinf(CC * L1), E2 = __sinf(CC * L2);
    const float I0 = E0 * Wi[0] + E1 * Wi[3] + E2 * Wi[6];
    const float I1 = E0 * Wi[1] + E1 * Wi[4] + E2 * Wi[7];
    const float I2 = E0 * Wi[2] + E1 * Wi[5] + E2 * Wi[8];
    float s0 = (L0 + E0 + I0) * (1.0f / 3.0f);
    float s1 = (L1 + E1 + I1) * (1.0f / 3.0f);
    float s2 = (L2 + E2 + I2) * (1.0f / 3.0f);

    float a0, a1, a2;

    // ---- layer 0: n=2, M=1, dbase=0 -> comb buf1 ----
    run_range<1, false>(W1_0, b1_0, W2_0, b2_0, nullptr,
                        (w * 2) >> 3, ((w + 1) * 2) >> 3,
                        s0, s1, s2, a0, a1, a2, diffp, 0, wg, lane);
    comb[1][w][0][lane] = a0; comb[1][w][1][lane] = a1; comb[1][w][2][lane] = a2;
    __syncthreads();
    s0 = s1 = s2 = 0.f;
    #pragma unroll
    for (int q = 0; q < 8; ++q) {
        s0 += comb[1][q][0][lane]; s1 += comb[1][q][1][lane]; s2 += comb[1][q][2][lane];
    }

    // ---- layer 1: n=12, M=2, dbase=1 -> comb buf0 ----
    run_range<2, true>(W1_1, b1_1, W2_1, b2_1, r0,
                       (w * 12) >> 3, ((w + 1) * 12) >> 3,
                       s0, s1, s2, a0, a1, a2, diffp, 1, wg, lane);
    comb[0][w][0][lane] = a0; comb[0][w][1][lane] = a1; comb[0][w][2][lane] = a2;
    __syncthreads();
    s0 = s1 = s2 = 0.f;
    #pragma unroll
    for (int q = 0; q < 8; ++q) {
        s0 += comb[0][q][0][lane]; s1 += comb[0][q][1][lane]; s2 += comb[0][q][2][lane];
    }

    // ---- layer 2: n=72, M=12, dbase=12 -> comb buf1 ----
    run_range<12, true>(W1_2, b1_2, W2_2, b2_2, r1,
                        w * 9, (w + 1) * 9,
                        s0, s1, s2, a0, a1, a2, diffp, 12, wg, lane);
    comb[1][w][0][lane] = a0; comb[1][w][1][lane] = a1; comb[1][w][2][lane] = a2;
    __syncthreads();
    s0 = s1 = s2 = 0.f;
    #pragma unroll
    for (int q = 0; q < 8; ++q) {
        s0 += comb[1][q][0][lane]; s1 += comb[1][q][1][lane]; s2 += comb[1][q][2][lane];
    }

    // ---- layer 3: n=432, M=72, dbase=83 -> comb buf0 ----
    run_range<72, true>(W1_3, b1_3, W2_3, b2_3, r2,
                        w * 54, (w + 1) * 54,
                        s0, s1, s2, a0, a1, a2, diffp, 83, wg, lane);
    comb[0][w][0][lane] = a0; comb[0][w][1][lane] = a1; comb[0][w][2][lane] = a2;
    __syncthreads();
    s0 = s1 = s2 = 0.f;
    #pragma unroll
    for (int q = 0; q < 8; ++q) {
        s0 += comb[0][q][0][lane]; s1 += comb[0][q][1][lane]; s2 += comb[0][q][2][lane];
    }

    if (w == 0) { Sout[0][lane] = s0; Sout[1][lane] = s1; Sout[2][lane] = s2; }
    __syncthreads();

    // ---- final matmul, coalesced: wave w writes rows w, w+8, ..., w+56 ----
    float4 wf0, wf1, wf2, bfv;
    if (lane < 45) {
        wf0 = *reinterpret_cast<const float4*>(wfe + 4 * lane);
        wf1 = *reinterpret_cast<const float4*>(wfe + 180 + 4 * lane);
        wf2 = *reinterpret_cast<const float4*>(wfe + 360 + 4 * lane);
        bfv = *reinterpret_cast<const float4*>(b_final + 4 * lane);
    }
    #pragma unroll
    for (int t = 0; t < 8; ++t) {
        const int r = w + 8 * t;
        const float q0 = Sout[0][r], q1 = Sout[1][r], q2 = Sout[2][r];
        if (lane < 45) {
            float4 o;
            o.x = bfv.x + q0 * wf0.x + q1 * wf1.x + q2 * wf2.x;
            o.y = bfv.y + q0 * wf0.y + q1 * wf1.y + q2 * wf2.y;
            o.z = bfv.z + q0 * wf0.z + q1 * wf1.z + q2 * wf2.z;
            o.w = bfv.w + q0 * wf0.w + q1 * wf1.w + q2 * wf2.w;
            *reinterpret_cast<float4*>(out + (size_t)(wg * 64 + r) * 180 + 4 * lane) = o;
        }
    }
}

// One block per stab entry: sum the 1024 per-WG partials, write stab.
__global__ __launch_bounds__(256) void reduce_stab(const float* __restrict__ diffp,
                                                   float* __restrict__ stab)
{
    const int k = blockIdx.x;
    int pos, dbase;
    if (k < 2)       { pos = k;      dbase = 0;  }
    else if (k < 14) { pos = k - 2;  dbase = 1;  }
    else if (k < 86) { pos = k - 14; dbase = 12; }
    else             { pos = k - 86; dbase = 83; }
    if (pos == 0) { if (threadIdx.x == 0) stab[k] = 1.0f; return; }

    const int d = dbase + pos - 1;
    const int t = threadIdx.x;
    const float* __restrict__ p = diffp + (size_t)d * NWG;
    float s = p[t] + p[t + 256] + p[t + 512] + p[t + 768];
    #pragma unroll
    for (int off = 32; off; off >>= 1) s += __shfl_xor(s, off);
    __shared__ float red[4];
    if ((t & 63) == 0) red[t >> 6] = s;
    __syncthreads();
    if (t == 0) {
        const float tot = red[0] + red[1] + red[2] + red[3];
        stab[k] = fmaxf(0.0f, 1.0f - tot * (1.0f / 196608.0f));
    }
}

extern "C" void kernel_launch(void* const* d_in, const int* in_sizes, int n_in,
                              void* d_out, int out_size, void* d_ws, size_t ws_size,
                              hipStream_t stream)
{
    const float* x    = (const float*)d_in[0];
    const float* Wl   = (const float*)d_in[1];
    const float* Wi   = (const float*)d_in[2];
    const float* W1_0 = (const float*)d_in[3];
    const float* b1_0 = (const float*)d_in[4];
    const float* W2_0 = (const float*)d_in[5];
    const float* b2_0 = (const float*)d_in[6];
    const float* R0   = (const float*)d_in[7];
    const float* W1_1 = (const float*)d_in[8];
    const float* b1_1 = (const float*)d_in[9];
    const float* W2_1 = (const float*)d_in[10];
    const float* b2_1 = (const float*)d_in[11];
    const float* R1   = (const float*)d_in[12];
    const float* W1_2 = (const float*)d_in[13];
    const float* b1_2 = (const float*)d_in[14];
    const float* W2_2 = (const float*)d_in[15];
    const float* b2_2 = (const float*)d_in[16];
    const float* R2   = (const float*)d_in[17];
    const float* W1_3 = (const float*)d_in[18];
    const float* b1_3 = (const float*)d_in[19];
    const float* W2_3 = (const float*)d_in[20];
    const float* b2_3 = (const float*)d_in[21];
    const float* R3   = (const float*)d_in[22];
    const float* Wf   = (const float*)d_in[23];
    const float* bf   = (const float*)d_in[24];

    float* out = (float*)d_out;
    float* ws  = (float*)d_ws;

    precompute_r<<<dim3(3), dim3(256), 0, stream>>>(R0, R1, R2, R3, ws);
    precompute_wfe<<<dim3(3), dim3(256), 0, stream>>>(Wf, ws + WS_R3, ws + WS_WFE);
    fractal_main<<<dim3(NWG), dim3(512), 0, stream>>>(
        x, Wl, Wi,
        W1_0, b1_0, W2_0, b2_0,
        W1_1, b1_1, W2_1, b2_1,
        W1_2, b1_2, W2_2, b2_2,
        W1_3, b1_3, W2_3, b2_3,
        bf,
        ws + WS_PART, ws + WS_R0, ws + WS_R1, ws + WS_R2, ws + WS_WFE,
        out);
    reduce_stab<<<dim3(518), dim3(256), 0, stream>>>(ws + WS_PART, out + (size_t)BATCH * 180);
}

// Round 8
// 259.169 us; speedup vs baseline: 5.5003x; 1.1110x over previous
//
#include <hip/hip_runtime.h>
#include <math.h>

#define BATCH  65536
#define NWG    1024          // fractal_main workgroups; one WG owns 64 batch elems
#define NDIFF  514           // (2-1)+(12-1)+(72-1)+(432-1)

// ws layout (floats), offsets kept 16B-aligned where float4 loads occur:
#define WS_PART 0
#define WS_R0   (NDIFF * NWG)          // 526336
#define WS_R1   (WS_R0 + 4)            // pad 2->4
#define WS_R2   (WS_R1 + 12)
#define WS_R3   (WS_R2 + 72)
#define WS_WFE  (WS_R3 + 432)          // byte offset % 16 == 0

__device__ __forceinline__ float fast_tanh(float x) {
    float e = __expf(2.0f * x);
    return 1.0f - 2.0f * __builtin_amdgcn_rcpf(e + 1.0f);
}

// 4 DPP stages: xor1 (quad_perm 1,0,3,2), xor2 (quad_perm 2,3,0,1),
// xor7 (row_half_mirror), +8 mod16 (row_ror:8) -> each lane = its 16-group sum.
__device__ __forceinline__ float dpp_sum16(float v) {
    int t;
    t = __builtin_amdgcn_update_dpp(0, __float_as_int(v), 0xB1,  0xF, 0xF, true);
    v += __int_as_float(t);
    t = __builtin_amdgcn_update_dpp(0, __float_as_int(v), 0x4E,  0xF, 0xF, true);
    v += __int_as_float(t);
    t = __builtin_amdgcn_update_dpp(0, __float_as_int(v), 0x141, 0xF, 0xF, true);
    v += __int_as_float(t);
    t = __builtin_amdgcn_update_dpp(0, __float_as_int(v), 0x128, 0xF, 0xF, true);
    v += __int_as_float(t);
    return v;
}

// Compute one fractal block j: input = c*S, output o0..o2.
__device__ __forceinline__ void block_fwd(
    const float* __restrict__ W1, const float* __restrict__ b1,
    const float* __restrict__ W2, const float* __restrict__ b2,
    int j, float c, float s0, float s1, float s2,
    float& o0, float& o1, float& o2)
{
    const float t0 = c * s0, t1 = c * s1, t2 = c * s2;
    const float* __restrict__ w1 = W1 + j * 9;
    const float* __restrict__ w2 = W2 + j * 9;
    const float* __restrict__ B1 = b1 + j * 3;
    const float* __restrict__ B2 = b2 + j * 3;
    float h0 = fast_tanh(B1[0] + t0 * w1[0] + t1 * w1[3] + t2 * w1[6]);
    float h1 = fast_tanh(B1[1] + t0 * w1[1] + t1 * w1[4] + t2 * w1[7]);
    float h2 = fast_tanh(B1[2] + t0 * w1[2] + t1 * w1[5] + t2 * w1[8]);
    o0 = B2[0] + h0 * w2[0] + h1 * w2[3] + h2 * w2[6];
    o1 = B2[1] + h0 * w2[1] + h1 * w2[4] + h2 * w2[7];
    o2 = B2[2] + h0 * w2[2] + h1 * w2[5] + h2 * w2[8];
}

// Wave-local slice [lo,hi) of one expander layer. 16-j chunks: per j, 4 DPP
// stages + masked LDS stash; per chunk, one LDS read + 2 DPP + masked store.
template<int M, bool HASR>
__device__ __forceinline__ void run_range(
    const float* __restrict__ W1, const float* __restrict__ b1,
    const float* __restrict__ W2, const float* __restrict__ b2,
    const float* __restrict__ rprev,
    int lo, int hi,
    float s0, float s1, float s2,
    float& a0, float& a1, float& a2,
    float* __restrict__ diffp, int dbase, int wg, int lane,
    float* __restrict__ dchunk)     // this wave's private [64] LDS row
{
    a0 = 0.f; a1 = 0.f; a2 = 0.f;
    if (lo >= hi) return;                      // wave-uniform
    float p0 = 0.f, p1 = 0.f, p2 = 0.f;
    if (lo > 0) {                              // prologue for first diff
        const int il = (lo - 1) % M;
        const float c = HASR ? rprev[il] : 1.0f;
        block_fwd(W1, b1, W2, b2, lo - 1, c, s0, s1, s2, p0, p1, p2);
    }
    int i = lo % M;
    for (int cb = lo; cb < hi; cb += 16) {
        const int ce = min(cb + 16, hi);
        #pragma unroll 4
        for (int j = cb; j < ce; ++j) {
            const float c = HASR ? rprev[i] : 1.0f;
            float o0, o1, o2;
            block_fwd(W1, b1, W2, b2, j, c, s0, s1, s2, o0, o1, o2);
            a0 += o0; a1 += o1; a2 += o2;
            float d = fabsf(o0 - p0) + fabsf(o1 - p1) + fabsf(o2 - p2);
            d = dpp_sum16(d);
            if ((lane & 15) == 0) dchunk[(j - cb) * 4 + (lane >> 4)] = d;
            p0 = o0; p1 = o1; p2 = o2;
            if (++i == M) i = 0;
        }
        // flush: slot layout is linear, lane l holds (jj=l>>2, g=l&3)
        float v = dchunk[lane];
        int t;
        t = __builtin_amdgcn_update_dpp(0, __float_as_int(v), 0xB1, 0xF, 0xF, true);
        v += __int_as_float(t);
        t = __builtin_amdgcn_update_dpp(0, __float_as_int(v), 0x4E, 0xF, 0xF, true);
        v += __int_as_float(t);
        const int j = cb + (lane >> 2);
        if ((lane & 3) == 0 && j < ce && j > 0)
            diffp[(size_t)(dbase + j - 1) * NWG + wg] = v;
    }
}

// One wave per row: coalesced row-sum + butterfly.
__global__ __launch_bounds__(256) void precompute_r(
    const float* __restrict__ R0, const float* __restrict__ R1,
    const float* __restrict__ R2, const float* __restrict__ R3,
    float* __restrict__ ws)
{
    const int gw   = (blockIdx.x * 256 + threadIdx.x) >> 6;
    const int lane = threadIdx.x & 63;
    if (gw >= 518) return;
    const float* src; int len, dst;
    if (gw < 2)       { src = R0 + gw * 2;          len = 2;   dst = WS_R0 + gw; }
    else if (gw < 14) { src = R1 + (gw - 2) * 12;   len = 12;  dst = WS_R1 + gw - 2; }
    else if (gw < 86) { src = R2 + (gw - 14) * 72;  len = 72;  dst = WS_R2 + gw - 14; }
    else              { src = R3 + (gw - 86) * 432; len = 432; dst = WS_R3 + gw - 86; }
    float s = 0.f;
    for (int i = lane; i < len; i += 64) s += src[i];
    #pragma unroll
    for (int off = 32; off; off >>= 1) s += __shfl_xor(s, off);
    if (lane == 0) ws[dst] = s;
}

// One wave per output element: Wfe[f*180+o] = sum_i r3[i]*Wf[(3i+f)*180+o]
__global__ __launch_bounds__(256) void precompute_wfe(
    const float* __restrict__ Wf, const float* __restrict__ r3,
    float* __restrict__ wfe)
{
    const int gw   = (blockIdx.x * 256 + threadIdx.x) >> 6;
    const int lane = threadIdx.x & 63;
    if (gw >= 540) return;
    const int f = gw / 180, o = gw - f * 180;
    float s = 0.f;
    for (int i = lane; i < 432; i += 64) s += r3[i] * Wf[(3 * i + f) * 180 + o];
    #pragma unroll
    for (int off = 32; off; off >>= 1) s += __shfl_xor(s, off);
    if (lane == 0) wfe[gw] = s;
}

__global__ __launch_bounds__(512, 8) void fractal_main(
    const float* __restrict__ x,
    const float* __restrict__ Wl, const float* __restrict__ Wi,
    const float* __restrict__ W1_0, const float* __restrict__ b1_0,
    const float* __restrict__ W2_0, const float* __restrict__ b2_0,
    const float* __restrict__ W1_1, const float* __restrict__ b1_1,
    const float* __restrict__ W2_1, const float* __restrict__ b2_1,
    const float* __restrict__ W1_2, const float* __restrict__ b1_2,
    const float* __restrict__ W2_2, const float* __restrict__ b2_2,
    const float* __restrict__ W1_3, const float* __restrict__ b1_3,
    const float* __restrict__ W2_3, const float* __restrict__ b2_3,
    const float* __restrict__ b_final,
    float* __restrict__ diffp,
    const float* __restrict__ r0, const float* __restrict__ r1,
    const float* __restrict__ r2, const float* __restrict__ wfe,
    float* __restrict__ out)
{
    __shared__ float comb[2][8][3][64];   // [buf][wave][component][lane]
    __shared__ float Sout[3][64];
    __shared__ float dchunk[8][64];       // per-wave diff staging

    const int lane = threadIdx.x & 63;
    const int w    = threadIdx.x >> 6;    // wave id 0..7
    const int wg   = blockIdx.x;
    const int b    = wg * 64 + lane;

    // ---- trinity seed, split over waves ----
    const float* __restrict__ xr = x + (size_t)b * 90;
    float L0 = 0.f, L1 = 0.f, L2 = 0.f;
    for (int k = w; k < 45; k += 8) {
        const float2 xv = *reinterpret_cast<const float2*>(xr + 2 * k);
        const float* __restrict__ wl = Wl + 6 * k;
        L0 += xv.x * wl[0] + xv.y * wl[3];
        L1 += xv.x * wl[1] + xv.y * wl[4];
        L2 += xv.x * wl[2] + xv.y * wl[5];
    }
    comb[0][w][0][lane] = L0; comb[0][w][1][lane] = L1; comb[0][w][2][lane] = L2;
    __syncthreads();
    L0 = L1 = L2 = 0.f;
    #pragma unroll
    for (int q = 0; q < 8; ++q) {
        L0 += comb[0][q][0][lane];
        L1 += comb[0][q][1][lane];
        L2 += comb[0][q][2][lane];
    }
    const float CC = 2.0943951023931953f; // 2*pi/3
    const float E0 = __sinf(CC * L0), E1 = __sinf(CC * L1), E2 = __sinf(CC * L2);
    const float I0 = E0 * Wi[0] + E1 * Wi[3] + E2 * Wi[6];
    const float I1 = E0 * Wi[1] + E1 * Wi[4] + E2 * Wi[7];
    const float I2 = E0 * Wi[2] + E1 * Wi[5] + E2 * Wi[8];
    float s0 = (L0 + E0 + I0) * (1.0f / 3.0f);
    float s1 = (L1 + E1 + I1) * (1.0f / 3.0f);
    float s2 = (L2 + E2 + I2) * (1.0f / 3.0f);

    float a0, a1, a2;

    // ---- layer 0: n=2, M=1, dbase=0 ----
    run_range<1, false>(W1_0, b1_0, W2_0, b2_0, nullptr,
                        (w * 2) >> 3, ((w + 1) * 2) >> 3,
                        s0, s1, s2, a0, a1, a2, diffp, 0, wg, lane, dchunk[w]);
    comb[1][w][0][lane] = a0; comb[1][w][1][lane] = a1; comb[1][w][2][lane] = a2;
    __syncthreads();
    s0 = s1 = s2 = 0.f;
    #pragma unroll
    for (int q = 0; q < 8; ++q) {
        s0 += comb[1][q][0][lane]; s1 += comb[1][q][1][lane]; s2 += comb[1][q][2][lane];
    }

    // ---- layer 1: n=12, M=2, dbase=1 ----
    run_range<2, true>(W1_1, b1_1, W2_1, b2_1, r0,
                       (w * 12) >> 3, ((w + 1) * 12) >> 3,
                       s0, s1, s2, a0, a1, a2, diffp, 1, wg, lane, dchunk[w]);
    comb[0][w][0][lane] = a0; comb[0][w][1][lane] = a1; comb[0][w][2][lane] = a2;
    __syncthreads();
    s0 = s1 = s2 = 0.f;
    #pragma unroll
    for (int q = 0; q < 8; ++q) {
        s0 += comb[0][q][0][lane]; s1 += comb[0][q][1][lane]; s2 += comb[0][q][2][lane];
    }

    // ---- layer 2: n=72, M=12, dbase=12 ----
    run_range<12, true>(W1_2, b1_2, W2_2, b2_2, r1,
                        w * 9, (w + 1) * 9,
                        s0, s1, s2, a0, a1, a2, diffp, 12, wg, lane, dchunk[w]);
    comb[1][w][0][lane] = a0; comb[1][w][1][lane] = a1; comb[1][w][2][lane] = a2;
    __syncthreads();
    s0 = s1 = s2 = 0.f;
    #pragma unroll
    for (int q = 0; q < 8; ++q) {
        s0 += comb[1][q][0][lane]; s1 += comb[1][q][1][lane]; s2 += comb[1][q][2][lane];
    }

    // ---- layer 3: n=432, M=72, dbase=83 ----
    run_range<72, true>(W1_3, b1_3, W2_3, b2_3, r2,
                        w * 54, (w + 1) * 54,
                        s0, s1, s2, a0, a1, a2, diffp, 83, wg, lane, dchunk[w]);
    comb[0][w][0][lane] = a0; comb[0][w][1][lane] = a1; comb[0][w][2][lane] = a2;
    __syncthreads();
    s0 = s1 = s2 = 0.f;
    #pragma unroll
    for (int q = 0; q < 8; ++q) {
        s0 += comb[0][q][0][lane]; s1 += comb[0][q][1][lane]; s2 += comb[0][q][2][lane];
    }

    if (w == 0) { Sout[0][lane] = s0; Sout[1][lane] = s1; Sout[2][lane] = s2; }
    __syncthreads();

    // ---- final matmul, coalesced: wave w writes rows w, w+8, ..., w+56 ----
    float4 wf0, wf1, wf2, bfv;
    if (lane < 45) {
        wf0 = *reinterpret_cast<const float4*>(wfe + 4 * lane);
        wf1 = *reinterpret_cast<const float4*>(wfe + 180 + 4 * lane);
        wf2 = *reinterpret_cast<const float4*>(wfe + 360 + 4 * lane);
        bfv = *reinterpret_cast<const float4*>(b_final + 4 * lane);
    }
    #pragma unroll
    for (int t = 0; t < 8; ++t) {
        const int r = w + 8 * t;
        const float q0 = Sout[0][r], q1 = Sout[1][r], q2 = Sout[2][r];
        if (lane < 45) {
            float4 o;
            o.x = bfv.x + q0 * wf0.x + q1 * wf1.x + q2 * wf2.x;
            o.y = bfv.y + q0 * wf0.y + q1 * wf1.y + q2 * wf2.y;
            o.z = bfv.z + q0 * wf0.z + q1 * wf1.z + q2 * wf2.z;
            o.w = bfv.w + q0 * wf0.w + q1 * wf1.w + q2 * wf2.w;
            *reinterpret_cast<float4*>(out + (size_t)(wg * 64 + r) * 180 + 4 * lane) = o;
        }
    }
}

// One block per stab entry: sum the 1024 per-WG partials, write stab.
__global__ __launch_bounds__(256) void reduce_stab(const float* __restrict__ diffp,
                                                   float* __restrict__ stab)
{
    const int k = blockIdx.x;
    int pos, dbase;
    if (k < 2)       { pos = k;      dbase = 0;  }
    else if (k < 14) { pos = k - 2;  dbase = 1;  }
    else if (k < 86) { pos = k - 14; dbase = 12; }
    else             { pos = k - 86; dbase = 83; }
    if (pos == 0) { if (threadIdx.x == 0) stab[k] = 1.0f; return; }

    const int d = dbase + pos - 1;
    const int t = threadIdx.x;
    const float* __restrict__ p = diffp + (size_t)d * NWG;
    float s = p[t] + p[t + 256] + p[t + 512] + p[t + 768];
    #pragma unroll
    for (int off = 32; off; off >>= 1) s += __shfl_xor(s, off);
    __shared__ float red[4];
    if ((t & 63) == 0) red[t >> 6] = s;
    __syncthreads();
    if (t == 0) {
        const float tot = red[0] + red[1] + red[2] + red[3];
        stab[k] = fmaxf(0.0f, 1.0f - tot * (1.0f / 196608.0f));
    }
}

extern "C" void kernel_launch(void* const* d_in, const int* in_sizes, int n_in,
                              void* d_out, int out_size, void* d_ws, size_t ws_size,
                              hipStream_t stream)
{
    const float* x    = (const float*)d_in[0];
    const float* Wl   = (const float*)d_in[1];
    const float* Wi   = (const float*)d_in[2];
    const float* W1_0 = (const float*)d_in[3];
    const float* b1_0 = (const float*)d_in[4];
    const float* W2_0 = (const float*)d_in[5];
    const float* b2_0 = (const float*)d_in[6];
    const float* R0   = (const float*)d_in[7];
    const float* W1_1 = (const float*)d_in[8];
    const float* b1_1 = (const float*)d_in[9];
    const float* W2_1 = (const float*)d_in[10];
    const float* b2_1 = (const float*)d_in[11];
    const float* R1   = (const float*)d_in[12];
    const float* W1_2 = (const float*)d_in[13];
    const float* b1_2 = (const float*)d_in[14];
    const float* W2_2 = (const float*)d_in[15];
    const float* b2_2 = (const float*)d_in[16];
    const float* R2   = (const float*)d_in[17];
    const float* W1_3 = (const float*)d_in[18];
    const float* b1_3 = (const float*)d_in[19];
    const float* W2_3 = (const float*)d_in[20];
    const float* b2_3 = (const float*)d_in[21];
    const float* R3   = (const float*)d_in[22];
    const float* Wf   = (const float*)d_in[23];
    const float* bf   = (const float*)d_in[24];

    float* out = (float*)d_out;
    float* ws  = (float*)d_ws;

    precompute_r<<<dim3(130), dim3(256), 0, stream>>>(R0, R1, R2, R3, ws);
    precompute_wfe<<<dim3(135), dim3(256), 0, stream>>>(Wf, ws + WS_R3, ws + WS_WFE);
    fractal_main<<<dim3(NWG), dim3(512), 0, stream>>>(
        x, Wl, Wi,
        W1_0, b1_0, W2_0, b2_0,
        W1_1, b1_1, W2_1, b2_1,
        W1_2, b1_2, W2_2, b2_2,
        W1_3, b1_3, W2_3, b2_3,
        bf,
        ws + WS_PART, ws + WS_R0, ws + WS_R1, ws + WS_R2, ws + WS_WFE,
        out);
    reduce_stab<<<dim3(518), dim3(256), 0, stream>>>(ws + WS_PART, out + (size_t)BATCH * 180);
}

// Round 10
// 215.198 us; speedup vs baseline: 6.6242x; 1.2043x over previous
//
#include <hip/hip_runtime.h>
#include <math.h>

#define BATCH  65536
#define NWG    1024          // fractal_main workgroups; one WG owns 64 batch elems
#define NDIFF  514           // (2-1)+(12-1)+(72-1)+(432-1)

// ws layout (floats), offsets kept 16B-aligned where float4 loads occur:
#define WS_PART 0
#define WS_R0   (NDIFF * NWG)          // 526336
#define WS_R1   (WS_R0 + 4)            // pad 2->4
#define WS_R2   (WS_R1 + 12)
#define WS_R3   (WS_R2 + 72)
#define WS_WFE  (WS_R3 + 432)          // byte offset % 16 == 0

__device__ __forceinline__ float fast_tanh(float x) {
    float e = __expf(2.0f * x);
    return 1.0f - 2.0f * __builtin_amdgcn_rcpf(e + 1.0f);
}

// 4 DPP stages: xor1 (quad_perm 1,0,3,2), xor2 (quad_perm 2,3,0,1),
// xor7 (row_half_mirror), +8 mod16 (row_ror:8) -> each lane = its 16-group sum.
__device__ __forceinline__ float dpp_sum16(float v) {
    int t;
    t = __builtin_amdgcn_update_dpp(0, __float_as_int(v), 0xB1,  0xF, 0xF, true);
    v += __int_as_float(t);
    t = __builtin_amdgcn_update_dpp(0, __float_as_int(v), 0x4E,  0xF, 0xF, true);
    v += __int_as_float(t);
    t = __builtin_amdgcn_update_dpp(0, __float_as_int(v), 0x141, 0xF, 0xF, true);
    v += __int_as_float(t);
    t = __builtin_amdgcn_update_dpp(0, __float_as_int(v), 0x128, 0xF, 0xF, true);
    v += __int_as_float(t);
    return v;
}

// Compute one fractal block sj (SCALAR index -> s_load weight fetch).
__device__ __forceinline__ void block_fwd(
    const float* __restrict__ W1, const float* __restrict__ b1,
    const float* __restrict__ W2, const float* __restrict__ b2,
    int sj, float c, float s0, float s1, float s2,
    float& o0, float& o1, float& o2)
{
    const float t0 = c * s0, t1 = c * s1, t2 = c * s2;
    const float* __restrict__ w1 = W1 + sj * 9;
    const float* __restrict__ w2 = W2 + sj * 9;
    const float* __restrict__ B1 = b1 + sj * 3;
    const float* __restrict__ B2 = b2 + sj * 3;
    float h0 = fast_tanh(B1[0] + t0 * w1[0] + t1 * w1[3] + t2 * w1[6]);
    float h1 = fast_tanh(B1[1] + t0 * w1[1] + t1 * w1[4] + t2 * w1[7]);
    float h2 = fast_tanh(B1[2] + t0 * w1[2] + t1 * w1[5] + t2 * w1[8]);
    o0 = B2[0] + h0 * w2[0] + h1 * w2[3] + h2 * w2[6];
    o1 = B2[1] + h0 * w2[1] + h1 * w2[4] + h2 * w2[7];
    o2 = B2[2] + h0 * w2[2] + h1 * w2[5] + h2 * w2[8];
}

// Wave-local slice [lo,hi) of one expander layer. Indices forced to SGPRs via
// readfirstlane (wave-uniform by construction) so weights come via s_load.
template<int M, bool HASR>
__device__ __forceinline__ void run_range(
    const float* __restrict__ W1, const float* __restrict__ b1,
    const float* __restrict__ W2, const float* __restrict__ b2,
    const float* __restrict__ rprev,
    int lo, int hi,
    float s0, float s1, float s2,
    float& a0, float& a1, float& a2,
    float* __restrict__ diffp, int dbase, int wg, int lane,
    float* __restrict__ dchunk)     // this wave's private [64] LDS row
{
    a0 = 0.f; a1 = 0.f; a2 = 0.f;
    if (lo >= hi) return;                      // wave-uniform
    float p0 = 0.f, p1 = 0.f, p2 = 0.f;
    if (lo > 0) {                              // prologue for first diff
        const int sj = __builtin_amdgcn_readfirstlane(lo - 1);
        const int si = __builtin_amdgcn_readfirstlane((lo - 1) % M);
        const float c = HASR ? rprev[si] : 1.0f;
        block_fwd(W1, b1, W2, b2, sj, c, s0, s1, s2, p0, p1, p2);
    }
    int i = lo % M;
    for (int cb = lo; cb < hi; cb += 16) {
        const int ce = min(cb + 16, hi);
        #pragma unroll 4
        for (int j = cb; j < ce; ++j) {
            const int sj = __builtin_amdgcn_readfirstlane(j);
            const int si = __builtin_amdgcn_readfirstlane(i);
            const float c = HASR ? rprev[si] : 1.0f;
            float o0, o1, o2;
            block_fwd(W1, b1, W2, b2, sj, c, s0, s1, s2, o0, o1, o2);
            a0 += o0; a1 += o1; a2 += o2;
            float d = fabsf(o0 - p0) + fabsf(o1 - p1) + fabsf(o2 - p2);
            d = dpp_sum16(d);
            if ((lane & 15) == 0) dchunk[(j - cb) * 4 + (lane >> 4)] = d;
            p0 = o0; p1 = o1; p2 = o2;
            if (++i == M) i = 0;
        }
        // flush: slot layout is linear, lane l holds (jj=l>>2, g=l&3)
        float v = dchunk[lane];
        int t;
        t = __builtin_amdgcn_update_dpp(0, __float_as_int(v), 0xB1, 0xF, 0xF, true);
        v += __int_as_float(t);
        t = __builtin_amdgcn_update_dpp(0, __float_as_int(v), 0x4E, 0xF, 0xF, true);
        v += __int_as_float(t);
        const int j = cb + (lane >> 2);
        if ((lane & 3) == 0 && j < ce && j > 0)
            diffp[(size_t)(dbase + j - 1) * NWG + wg] = v;
    }
}

// One wave per row: coalesced row-sum + butterfly.
__global__ __launch_bounds__(256) void precompute_r(
    const float* __restrict__ R0, const float* __restrict__ R1,
    const float* __restrict__ R2, const float* __restrict__ R3,
    float* __restrict__ ws)
{
    const int gw   = (blockIdx.x * 256 + threadIdx.x) >> 6;
    const int lane = threadIdx.x & 63;
    if (gw >= 518) return;
    const float* src; int len, dst;
    if (gw < 2)       { src = R0 + gw * 2;          len = 2;   dst = WS_R0 + gw; }
    else if (gw < 14) { src = R1 + (gw - 2) * 12;   len = 12;  dst = WS_R1 + gw - 2; }
    else if (gw < 86) { src = R2 + (gw - 14) * 72;  len = 72;  dst = WS_R2 + gw - 14; }
    else              { src = R3 + (gw - 86) * 432; len = 432; dst = WS_R3 + gw - 86; }
    float s = 0.f;
    for (int i = lane; i < len; i += 64) s += src[i];
    #pragma unroll
    for (int off = 32; off; off >>= 1) s += __shfl_xor(s, off);
    if (lane == 0) ws[dst] = s;
}

// One wave per output element: Wfe[f*180+o] = sum_i r3[i]*Wf[(3i+f)*180+o]
__global__ __launch_bounds__(256) void precompute_wfe(
    const float* __restrict__ Wf, const float* __restrict__ r3,
    float* __restrict__ wfe)
{
    const int gw   = (blockIdx.x * 256 + threadIdx.x) >> 6;
    const int lane = threadIdx.x & 63;
    if (gw >= 540) return;
    const int f = gw / 180, o = gw - f * 180;
    float s = 0.f;
    for (int i = lane; i < 432; i += 64) s += r3[i] * Wf[(3 * i + f) * 180 + o];
    #pragma unroll
    for (int off = 32; off; off >>= 1) s += __shfl_xor(s, off);
    if (lane == 0) wfe[gw] = s;
}

__global__ __launch_bounds__(512, 8) void fractal_main(
    const float* __restrict__ x,
    const float* __restrict__ Wl, const float* __restrict__ Wi,
    const float* __restrict__ W1_0, const float* __restrict__ b1_0,
    const float* __restrict__ W2_0, const float* __restrict__ b2_0,
    const float* __restrict__ W1_1, const float* __restrict__ b1_1,
    const float* __restrict__ W2_1, const float* __restrict__ b2_1,
    const float* __restrict__ W1_2, const float* __restrict__ b1_2,
    const float* __restrict__ W2_2, const float* __restrict__ b2_2,
    const float* __restrict__ W1_3, const float* __restrict__ b1_3,
    const float* __restrict__ W2_3, const float* __restrict__ b2_3,
    const float* __restrict__ b_final,
    float* __restrict__ diffp,
    const float* __restrict__ r0, const float* __restrict__ r1,
    const float* __restrict__ r2, const float* __restrict__ wfe,
    float* __restrict__ out)
{
    __shared__ float comb[2][8][3][64];   // [buf][wave][component][lane]
    __shared__ float Sout[3][64];
    __shared__ float dchunk[8][64];       // per-wave diff staging

    const int lane = threadIdx.x & 63;
    const int w    = threadIdx.x >> 6;    // wave id 0..7
    const int wg   = blockIdx.x;
    const int b    = wg * 64 + lane;

    // ---- trinity seed, split over waves ----
    const float* __restrict__ xr = x + (size_t)b * 90;
    float L0 = 0.f, L1 = 0.f, L2 = 0.f;
    for (int k = w; k < 45; k += 8) {
        const int ks = __builtin_amdgcn_readfirstlane(k);
        const float2 xv = *reinterpret_cast<const float2*>(xr + 2 * ks);
        const float* __restrict__ wl = Wl + 6 * ks;
        L0 += xv.x * wl[0] + xv.y * wl[3];
        L1 += xv.x * wl[1] + xv.y * wl[4];
        L2 += xv.x * wl[2] + xv.y * wl[5];
    }
    comb[0][w][0][lane] = L0; comb[0][w][1][lane] = L1; comb[0][w][2][lane] = L2;
    __syncthreads();
    L0 = L1 = L2 = 0.f;
    #pragma unroll
    for (int q = 0; q < 8; ++q) {
        L0 += comb[0][q][0][lane];
        L1 += comb[0][q][1][lane];
        L2 += comb[0][q][2][lane];
    }
    const float CC = 2.0943951023931953f; // 2*pi/3
    const float E0 = __sinf(CC * L0), E1 = __sinf(CC * L1), E2 = __sinf(CC * L2);
    const float I0 = E0 * Wi[0] + E1 * Wi[3] + E2 * Wi[6];
    const float I1 = E0 * Wi[1] + E1 * Wi[4] + E2 * Wi[7];
    const float I2 = E0 * Wi[2] + E1 * Wi[5] + E2 * Wi[8];
    float s0 = (L0 + E0 + I0) * (1.0f / 3.0f);
    float s1 = (L1 + E1 + I1) * (1.0f / 3.0f);
    float s2 = (L2 + E2 + I2) * (1.0f / 3.0f);

    float a0, a1, a2;

    // ---- layer 0: n=2, M=1, dbase=0 ----
    run_range<1, false>(W1_0, b1_0, W2_0, b2_0, nullptr,
                        (w * 2) >> 3, ((w + 1) * 2) >> 3,
                        s0, s1, s2, a0, a1, a2, diffp, 0, wg, lane, dchunk[w]);
    comb[1][w][0][lane] = a0; comb[1][w][1][lane] = a1; comb[1][w][2][lane] = a2;
    __syncthreads();
    s0 = s1 = s2 = 0.f;
    #pragma unroll
    for (int q = 0; q < 8; ++q) {
        s0 += comb[1][q][0][lane]; s1 += comb[1][q][1][lane]; s2 += comb[1][q][2][lane];
    }

    // ---- layer 1: n=12, M=2, dbase=1 ----
    run_range<2, true>(W1_1, b1_1, W2_1, b2_1, r0,
                       (w * 12) >> 3, ((w + 1) * 12) >> 3,
                       s0, s1, s2, a0, a1, a2, diffp, 1, wg, lane, dchunk[w]);
    comb[0][w][0][lane] = a0; comb[0][w][1][lane] = a1; comb[0][w][2][lane] = a2;
    __syncthreads();
    s0 = s1 = s2 = 0.f;
    #pragma unroll
    for (int q = 0; q < 8; ++q) {
        s0 += comb[0][q][0][lane]; s1 += comb[0][q][1][lane]; s2 += comb[0][q][2][lane];
    }

    // ---- layer 2: n=72, M=12, dbase=12 ----
    run_range<12, true>(W1_2, b1_2, W2_2, b2_2, r1,
                        w * 9, (w + 1) * 9,
                        s0, s1, s2, a0, a1, a2, diffp, 12, wg, lane, dchunk[w]);
    comb[1][w][0][lane] = a0; comb[1][w][1][lane] = a1; comb[1][w][2][lane] = a2;
    __syncthreads();
    s0 = s1 = s2 = 0.f;
    #pragma unroll
    for (int q = 0; q < 8; ++q) {
        s0 += comb[1][q][0][lane]; s1 += comb[1][q][1][lane]; s2 += comb[1][q][2][lane];
    }

    // ---- layer 3: n=432, M=72, dbase=83 ----
    run_range<72, true>(W1_3, b1_3, W2_3, b2_3, r2,
                        w * 54, (w + 1) * 54,
                        s0, s1, s2, a0, a1, a2, diffp, 83, wg, lane, dchunk[w]);
    comb[0][w][0][lane] = a0; comb[0][w][1][lane] = a1; comb[0][w][2][lane] = a2;
    __syncthreads();
    s0 = s1 = s2 = 0.f;
    #pragma unroll
    for (int q = 0; q < 8; ++q) {
        s0 += comb[0][q][0][lane]; s1 += comb[0][q][1][lane]; s2 += comb[0][q][2][lane];
    }

    if (w == 0) { Sout[0][lane] = s0; Sout[1][lane] = s1; Sout[2][lane] = s2; }
    __syncthreads();

    // ---- final matmul, coalesced: wave w writes rows w, w+8, ..., w+56 ----
    float4 wf0, wf1, wf2, bfv;
    if (lane < 45) {
        wf0 = *reinterpret_cast<const float4*>(wfe + 4 * lane);
        wf1 = *reinterpret_cast<const float4*>(wfe + 180 + 4 * lane);
        wf2 = *reinterpret_cast<const float4*>(wfe + 360 + 4 * lane);
        bfv = *reinterpret_cast<const float4*>(b_final + 4 * lane);
    }
    #pragma unroll
    for (int t = 0; t < 8; ++t) {
        const int r = w + 8 * t;
        const float q0 = Sout[0][r], q1 = Sout[1][r], q2 = Sout[2][r];
        if (lane < 45) {
            float4 o;
            o.x = bfv.x + q0 * wf0.x + q1 * wf1.x + q2 * wf2.x;
            o.y = bfv.y + q0 * wf0.y + q1 * wf1.y + q2 * wf2.y;
            o.z = bfv.z + q0 * wf0.z + q1 * wf1.z + q2 * wf2.z;
            o.w = bfv.w + q0 * wf0.w + q1 * wf1.w + q2 * wf2.w;
            *reinterpret_cast<float4*>(out + (size_t)(wg * 64 + r) * 180 + 4 * lane) = o;
        }
    }
}

// One block per stab entry: sum the 1024 per-WG partials, write stab.
__global__ __launch_bounds__(256) void reduce_stab(const float* __restrict__ diffp,
                                                   float* __restrict__ stab)
{
    const int k = blockIdx.x;
    int pos, dbase;
    if (k < 2)       { pos = k;      dbase = 0;  }
    else if (k < 14) { pos = k - 2;  dbase = 1;  }
    else if (k < 86) { pos = k - 14; dbase = 12; }
    else             { pos = k - 86; dbase = 83; }
    if (pos == 0) { if (threadIdx.x == 0) stab[k] = 1.0f; return; }

    const int d = dbase + pos - 1;
    const int t = threadIdx.x;
    const float* __restrict__ p = diffp + (size_t)d * NWG;
    float s = p[t] + p[t + 256] + p[t + 512] + p[t + 768];
    #pragma unroll
    for (int off = 32; off; off >>= 1) s += __shfl_xor(s, off);
    __shared__ float red[4];
    if ((t & 63) == 0) red[t >> 6] = s;
    __syncthreads();
    if (t == 0) {
        const float tot = red[0] + red[1] + red[2] + red[3];
        stab[k] = fmaxf(0.0f, 1.0f - tot * (1.0f / 196608.0f));
    }
}

extern "C" void kernel_launch(void* const* d_in, const int* in_sizes, int n_in,
                              void* d_out, int out_size, void* d_ws, size_t ws_size,
                              hipStream_t stream)
{
    const float* x    = (const float*)d_in[0];
    const float* Wl   = (const float*)d_in[1];
    const float* Wi   = (const float*)d_in[2];
    const float* W1_0 = (const float*)d_in[3];
    const float* b1_0 = (const float*)d_in[4];
    const float* W2_0 = (const float*)d_in[5];
    const float* b2_0 = (const float*)d_in[6];
    const float* R0   = (const float*)d_in[7];
    const float* W1_1 = (const float*)d_in[8];
    const float* b1_1 = (const float*)d_in[9];
    const float* W2_1 = (const float*)d_in[10];
    const float* b2_1 = (const float*)d_in[11];
    const float* R1   = (const float*)d_in[12];
    const float* W1_2 = (const float*)d_in[13];
    const float* b1_2 = (const float*)d_in[14];
    const float* W2_2 = (const float*)d_in[15];
    const float* b2_2 = (const float*)d_in[16];
    const float* R2   = (const float*)d_in[17];
    const float* W1_3 = (const float*)d_in[18];
    const float* b1_3 = (const float*)d_in[19];
    const float* W2_3 = (const float*)d_in[20];
    const float* b2_3 = (const float*)d_in[21];
    const float* R3   = (const float*)d_in[22];
    const float* Wf   = (const float*)d_in[23];
    const float* bf   = (const float*)d_in[24];

    float* out = (float*)d_out;
    float* ws  = (float*)d_ws;

    precompute_r<<<dim3(130), dim3(256), 0, stream>>>(R0, R1, R2, R3, ws);
    precompute_wfe<<<dim3(135), dim3(256), 0, stream>>>(Wf, ws + WS_R3, ws + WS_WFE);
    fractal_main<<<dim3(NWG), dim3(512), 0, stream>>>(
        x, Wl, Wi,
        W1_0, b1_0, W2_0, b2_0,
        W1_1, b1_1, W2_1, b2_1,
        W1_2, b1_2, W2_2, b2_2,
        W1_3, b1_3, W2_3, b2_3,
        bf,
        ws + WS_PART, ws + WS_R0, ws + WS_R1, ws + WS_R2, ws + WS_WFE,
        out);
    reduce_stab<<<dim3(518), dim3(256), 0, stream>>>(ws + WS_PART, out + (size_t)BATCH * 180);
}